// Round 4
// baseline (285.095 us; speedup 1.0000x reference)
//
#include <hip/hip_runtime.h>
#include <hip/hip_bf16.h>

// GIN: 2 x (padded-CSR gather-sum fused with MLP(64->64->64) + BN-stats) + mean pool
// N=50000 nodes, E=800000 edges, H=64, G=16 graphs. fp32 in/out.
// R18 = R17 fusion + race fix: layer-0's bf16 raw output goes to xb2 (NOT xb,
// which other blocks are still gathering from — that race was R17's 0.625
// absmax). layer 1 gathers from xb2.
// 6 dispatches: prep, scatter, layer0, layer1, norm, finalize.

constexpr int NN = 50000;
constexpr int NE = 800000;
constexpr int HD = 64;
constexpr int NG = 16;
constexpr float BN_EPS = 1e-5f;
constexpr int ROWCAP = 64;   // max degree capacity; P(deg>64)~1e-20 at E/N=16
constexpr int NPART = 8;     // XCD partitions (scatter locality)
constexpr int PSZ = 6250;    // rows per partition

__device__ __forceinline__ int rdl(int v, int l) {
    return __builtin_amdgcn_readlane(v, l);
}

// ---------------------------------------------------------------------------
// Prep: fp32 -> bf16 table conversion; zero cnt[], stats0/1, psums.
// ---------------------------------------------------------------------------
__global__ __launch_bounds__(256)
void prep_kernel(const float* __restrict__ x, __hip_bfloat16* __restrict__ xb,
                 int* __restrict__ cnt, float* __restrict__ stats0,
                 float* __restrict__ stats1, float* __restrict__ psums) {
    int i4 = blockIdx.x * 256 + threadIdx.x;
    if (i4 < NN) cnt[i4] = 0;
    if (blockIdx.x == 0) {
        if (threadIdx.x < 128) stats0[threadIdx.x] = 0.f;
        else stats1[threadIdx.x - 128] = 0.f;
    } else if (blockIdx.x == 1) {
        *(float4*)(psums + threadIdx.x * 4) = make_float4(0.f, 0.f, 0.f, 0.f);
    }
    if (i4 >= NN * HD / 4) return;
    float4 v = *(const float4*)(x + (size_t)i4 * 4);
    union { ushort4 u; __hip_bfloat16 b[4]; } p;
    p.b[0] = __float2bfloat16(v.x);
    p.b[1] = __float2bfloat16(v.y);
    p.b[2] = __float2bfloat16(v.z);
    p.b[3] = __float2bfloat16(v.w);
    *(ushort4*)((unsigned short*)xb + (size_t)i4 * 4) = p.u;
}

// ---------------------------------------------------------------------------
// XCD-partitioned scatter into degree-padded ushort CSR (R16, unchanged).
// Block b: partition b&7 (round-robin blockIdx->XCD), edge chunk b>>3.
// ---------------------------------------------------------------------------
__global__ __launch_bounds__(256)
void scatter_kernel(const int* __restrict__ ei, int* __restrict__ cnt,
                    unsigned short* __restrict__ csr) {
    int p = blockIdx.x & 7;
    int chunk = blockIdx.x >> 3;
    int e4 = (chunk * 256 + threadIdx.x) * 4;
    if (e4 >= NE) return;
    int4 s = *(const int4*)(ei + e4);
    int4 d = *(const int4*)(ei + NE + e4);
    int lo = p * PSZ, hi = lo + PSZ;
    int slot;
    if (d.x >= lo && d.x < hi) {
        slot = atomicAdd(&cnt[d.x], 1);
        if (slot < ROWCAP) csr[(d.x << 6) + slot] = (unsigned short)s.x;
    }
    if (d.y >= lo && d.y < hi) {
        slot = atomicAdd(&cnt[d.y], 1);
        if (slot < ROWCAP) csr[(d.y << 6) + slot] = (unsigned short)s.y;
    }
    if (d.z >= lo && d.z < hi) {
        slot = atomicAdd(&cnt[d.z], 1);
        if (slot < ROWCAP) csr[(d.z << 6) + slot] = (unsigned short)s.z;
    }
    if (d.w >= lo && d.w < hi) {
        slot = atomicAdd(&cnt[d.w], 1);
        if (slot < ROWCAP) csr[(d.w << 6) + slot] = (unsigned short)s.w;
    }
}

// ---------------------------------------------------------------------------
// Fused layer kernel: aggregate 128 rows into LDS, then MLP + BN-stats.
// MODE 0: self/gather raw (layer 0).  MODE 1: apply prev BN+ReLU on the fly.
// 512 threads = 8 waves; wave w aggregates rows [w*16, w*16+16) and computes
// output cols [w*8, w*8+8) in the GEMMs.
// xg (gather table) and xbr (bf16 output table) MUST be distinct buffers.
// ---------------------------------------------------------------------------
template <int MODE>
__global__ __launch_bounds__(512)
void layer_kernel(const float* __restrict__ xin, const __hip_bfloat16* __restrict__ xg,
                  const int* __restrict__ cnt, const unsigned short* __restrict__ csr,
                  const float* __restrict__ stats_prev, const float* __restrict__ gp,
                  const float* __restrict__ bep,
                  const float* __restrict__ W1, const float* __restrict__ b1,
                  const float* __restrict__ W2, const float* __restrict__ b2,
                  float* __restrict__ hout, float* __restrict__ stats,
                  __hip_bfloat16* __restrict__ xbr) {
    __shared__ float sh[128 * 65];
    __shared__ float sW[64 * 64];
    __shared__ float sb[64];
    __shared__ float red[2][8][64];
    int tid = threadIdx.x;
    int base = blockIdx.x * 128;
    int w = tid >> 6, lane = tid & 63;

    for (int i = tid; i < 4096; i += 512) sW[i] = W1[i];
    if (tid < 64) sb[tid] = b1[tid];

    float sc = 1.f, off = 0.f;
    if (MODE == 1) {
        const float inv = 1.f / (float)NN;
        float mu = stats_prev[lane] * inv;
        float var = stats_prev[64 + lane] * inv - mu * mu;
        sc = gp[lane] * rsqrtf(var + BN_EPS);
        off = bep[lane] - mu * sc;
    }

    // ---- aggregation: wave w fills sh rows [w*16, w*16+16) ----
    for (int rl = w * 16; rl < w * 16 + 16; rl++) {
        int grow = base + rl;
        float acc = 0.f;
        if (grow < NN) {
            int m = min(cnt[grow], ROWCAP);
            int ids = (int)csr[((size_t)grow << 6) + lane];
            float sv = xin[(size_t)grow * HD + lane];
            acc = (MODE == 1) ? fmaxf(fmaf(sv, sc, off), 0.f) : sv;
            int j = 0;
            float a0 = 0.f, a1 = 0.f, a2 = 0.f, a3 = 0.f;
            float a4 = 0.f, a5 = 0.f, a6 = 0.f, a7 = 0.f;
            for (; j + 8 <= m; j += 8) {
                int n0 = rdl(ids, j);
                int n1 = rdl(ids, j + 1);
                int n2 = rdl(ids, j + 2);
                int n3 = rdl(ids, j + 3);
                int n4 = rdl(ids, j + 4);
                int n5 = rdl(ids, j + 5);
                int n6 = rdl(ids, j + 6);
                int n7 = rdl(ids, j + 7);
                float v0 = __bfloat162float(xg[((size_t)n0 << 6) + lane]);
                float v1 = __bfloat162float(xg[((size_t)n1 << 6) + lane]);
                float v2 = __bfloat162float(xg[((size_t)n2 << 6) + lane]);
                float v3 = __bfloat162float(xg[((size_t)n3 << 6) + lane]);
                float v4 = __bfloat162float(xg[((size_t)n4 << 6) + lane]);
                float v5 = __bfloat162float(xg[((size_t)n5 << 6) + lane]);
                float v6 = __bfloat162float(xg[((size_t)n6 << 6) + lane]);
                float v7 = __bfloat162float(xg[((size_t)n7 << 6) + lane]);
                if (MODE == 1) {
                    a0 += fmaxf(fmaf(v0, sc, off), 0.f);
                    a1 += fmaxf(fmaf(v1, sc, off), 0.f);
                    a2 += fmaxf(fmaf(v2, sc, off), 0.f);
                    a3 += fmaxf(fmaf(v3, sc, off), 0.f);
                    a4 += fmaxf(fmaf(v4, sc, off), 0.f);
                    a5 += fmaxf(fmaf(v5, sc, off), 0.f);
                    a6 += fmaxf(fmaf(v6, sc, off), 0.f);
                    a7 += fmaxf(fmaf(v7, sc, off), 0.f);
                } else {
                    a0 += v0; a1 += v1; a2 += v2; a3 += v3;
                    a4 += v4; a5 += v5; a6 += v6; a7 += v7;
                }
            }
            acc += ((a0 + a1) + (a2 + a3)) + ((a4 + a5) + (a6 + a7));
            for (; j < m; j++) {
                int nb = rdl(ids, j);
                float v = __bfloat162float(xg[((size_t)nb << 6) + lane]);
                acc += (MODE == 1) ? fmaxf(fmaf(v, sc, off), 0.f) : v;
            }
        }
        sh[rl * 65 + lane] = acc;
    }
    __syncthreads();

    // ---- GEMM1: wave w -> output cols [w*8, w*8+8) ----
    float acc0[8], acc1[8];
#pragma unroll
    for (int j = 0; j < 8; j++) { acc0[j] = sb[w * 8 + j]; acc1[j] = acc0[j]; }
    for (int k = 0; k < 64; k++) {
        float a0 = sh[lane * 65 + k];
        float a1 = sh[(64 + lane) * 65 + k];
        const float4* wr = (const float4*)(sW + k * 64 + w * 8);
#pragma unroll
        for (int q = 0; q < 2; q++) {
            float4 wv = wr[q];
            acc0[4 * q + 0] = fmaf(a0, wv.x, acc0[4 * q + 0]);
            acc0[4 * q + 1] = fmaf(a0, wv.y, acc0[4 * q + 1]);
            acc0[4 * q + 2] = fmaf(a0, wv.z, acc0[4 * q + 2]);
            acc0[4 * q + 3] = fmaf(a0, wv.w, acc0[4 * q + 3]);
            acc1[4 * q + 0] = fmaf(a1, wv.x, acc1[4 * q + 0]);
            acc1[4 * q + 1] = fmaf(a1, wv.y, acc1[4 * q + 1]);
            acc1[4 * q + 2] = fmaf(a1, wv.z, acc1[4 * q + 2]);
            acc1[4 * q + 3] = fmaf(a1, wv.w, acc1[4 * q + 3]);
        }
    }
    __syncthreads();

    // t = ReLU(acc) overwrites sh; restage W2/b2
#pragma unroll
    for (int j = 0; j < 8; j++) {
        sh[lane * 65 + w * 8 + j] = fmaxf(acc0[j], 0.f);
        sh[(64 + lane) * 65 + w * 8 + j] = fmaxf(acc1[j], 0.f);
    }
    for (int i = tid; i < 4096; i += 512) sW[i] = W2[i];
    if (tid < 64) sb[tid] = b2[tid];
    __syncthreads();

    // ---- GEMM2 ----
#pragma unroll
    for (int j = 0; j < 8; j++) { acc0[j] = sb[w * 8 + j]; acc1[j] = acc0[j]; }
    for (int k = 0; k < 64; k++) {
        float a0 = sh[lane * 65 + k];
        float a1 = sh[(64 + lane) * 65 + k];
        const float4* wr = (const float4*)(sW + k * 64 + w * 8);
#pragma unroll
        for (int q = 0; q < 2; q++) {
            float4 wv = wr[q];
            acc0[4 * q + 0] = fmaf(a0, wv.x, acc0[4 * q + 0]);
            acc0[4 * q + 1] = fmaf(a0, wv.y, acc0[4 * q + 1]);
            acc0[4 * q + 2] = fmaf(a0, wv.z, acc0[4 * q + 2]);
            acc0[4 * q + 3] = fmaf(a0, wv.w, acc0[4 * q + 3]);
            acc1[4 * q + 0] = fmaf(a1, wv.x, acc1[4 * q + 0]);
            acc1[4 * q + 1] = fmaf(a1, wv.y, acc1[4 * q + 1]);
            acc1[4 * q + 2] = fmaf(a1, wv.z, acc1[4 * q + 2]);
            acc1[4 * q + 3] = fmaf(a1, wv.w, acc1[4 * q + 3]);
        }
    }
    __syncthreads();
#pragma unroll
    for (int j = 0; j < 8; j++) {
        sh[lane * 65 + w * 8 + j] = acc0[j];
        sh[(64 + lane) * 65 + w * 8 + j] = acc1[j];
    }
    __syncthreads();

    // ---- coalesced stores: fp32 always; bf16 raw table if requested ----
#pragma unroll
    for (int i = 0; i < 4; i++) {
        int i4 = tid + 512 * i;
        int row = i4 >> 4, col = (i4 & 15) * 4;
        int grow = base + row;
        if (grow < NN) {
            const float* s = sh + row * 65 + col;
            float4 v = make_float4(s[0], s[1], s[2], s[3]);
            *(float4*)(hout + (size_t)grow * HD + col) = v;
            if (xbr) {
                union { ushort4 u; __hip_bfloat16 b[4]; } p;
                p.b[0] = __float2bfloat16(v.x);
                p.b[1] = __float2bfloat16(v.y);
                p.b[2] = __float2bfloat16(v.z);
                p.b[3] = __float2bfloat16(v.w);
                *(ushort4*)((unsigned short*)xbr + (size_t)grow * HD + col) = p.u;
            }
        }
    }

    // ---- fused BN-stats partials (wave w sums its 16 rows) ----
    {
        float s = 0.f, ss = 0.f;
#pragma unroll
        for (int r = 0; r < 16; r++) {
            int rl = w * 16 + r;
            float v = (base + rl < NN) ? sh[rl * 65 + lane] : 0.f;
            s += v;
            ss += v * v;
        }
        red[0][w][lane] = s;
        red[1][w][lane] = ss;
        __syncthreads();
        if (tid < 64) {
            float S = 0.f;
#pragma unroll
            for (int q = 0; q < 8; q++) S += red[0][q][tid];
            atomicAdd(stats + tid, S);
        } else if (tid < 128) {
            int c = tid - 64;
            float SS = 0.f;
#pragma unroll
            for (int q = 0; q < 8; q++) SS += red[1][q][c];
            atomicAdd(stats + 64 + c, SS);
        }
    }
}

// ---------------------------------------------------------------------------
// Final BatchNorm + affine + ReLU, in-place on out, with fused mean-pool
// partials (LDS-reduce per-graph column sums, fire-and-forget atomics).
// ---------------------------------------------------------------------------
__global__ __launch_bounds__(256)
void norm_kernel(float* h, const float* __restrict__ stats,
                 const float* __restrict__ g, const float* __restrict__ be,
                 const int* __restrict__ batch, float* __restrict__ psums) {
    __shared__ float sg[2][64];
    if (threadIdx.x < 128) sg[threadIdx.x >> 6][threadIdx.x & 63] = 0.f;
    __syncthreads();
    size_t i4 = (size_t)blockIdx.x * 256 + threadIdx.x;
    int row = (int)(i4 >> 4);            // 16 threads (4 cols each) per row
    int base_row = blockIdx.x * 16;
    int g0 = batch[base_row];
    size_t off = i4 * 4;
    int col = (int)(off & 63);
    float4 v = *(const float4*)(h + off);
    float4 sm = *(const float4*)(stats + col);
    float4 sq = *(const float4*)(stats + 64 + col);
    float4 gg = *(const float4*)(g + col);
    float4 bb = *(const float4*)(be + col);
    const float inv = 1.f / (float)NN;
    float4 o;
    {
        float mu = sm.x * inv, var = sq.x * inv - mu * mu;
        float sc = gg.x * rsqrtf(var + BN_EPS);
        o.x = fmaxf((v.x - mu) * sc + bb.x, 0.f);
    }
    {
        float mu = sm.y * inv, var = sq.y * inv - mu * mu;
        float sc = gg.y * rsqrtf(var + BN_EPS);
        o.y = fmaxf((v.y - mu) * sc + bb.y, 0.f);
    }
    {
        float mu = sm.z * inv, var = sq.z * inv - mu * mu;
        float sc = gg.z * rsqrtf(var + BN_EPS);
        o.z = fmaxf((v.z - mu) * sc + bb.z, 0.f);
    }
    {
        float mu = sm.w * inv, var = sq.w * inv - mu * mu;
        float sc = gg.w * rsqrtf(var + BN_EPS);
        o.w = fmaxf((v.w - mu) * sc + bb.w, 0.f);
    }
    *(float4*)(h + off) = o;

    // pool partials
    int dg = batch[row] - g0;
    if (dg <= 1) {
        atomicAdd(&sg[dg][col + 0], o.x);
        atomicAdd(&sg[dg][col + 1], o.y);
        atomicAdd(&sg[dg][col + 2], o.z);
        atomicAdd(&sg[dg][col + 3], o.w);
    } else {  // >2 graphs in one 16-row window (never at ~3125 rows/graph)
        int gid = g0 + dg;
        atomicAdd(&psums[gid * HD + col + 0], o.x);
        atomicAdd(&psums[gid * HD + col + 1], o.y);
        atomicAdd(&psums[gid * HD + col + 2], o.z);
        atomicAdd(&psums[gid * HD + col + 3], o.w);
    }
    __syncthreads();
    if (threadIdx.x < 128) {
        int d = threadIdx.x >> 6;
        int c = threadIdx.x & 63;
        float s = sg[d][c];
        if (g0 + d < NG && s != 0.f) atomicAdd(&psums[(g0 + d) * HD + c], s);
    }
}

// ---------------------------------------------------------------------------
// Pool finalize: divide psums by graph sizes (batch sorted -> binary search).
// ---------------------------------------------------------------------------
__device__ __forceinline__ int lower_bound_batch(const int* __restrict__ b, int val) {
    int lo = 0, hi = NN;
    while (lo < hi) {
        int mid = (lo + hi) >> 1;
        if (b[mid] < val) lo = mid + 1;
        else hi = mid;
    }
    return lo;
}

__global__ __launch_bounds__(1024)
void pool_finalize_kernel(const float* __restrict__ sums, const int* __restrict__ batch,
                          float* __restrict__ out) {
    int g = threadIdx.x >> 6;
    int col = threadIdx.x & 63;
    int s = lower_bound_batch(batch, g);
    int e = lower_bound_batch(batch, g + 1);
    float cnt = (float)(e - s);
    out[g * HD + col] = sums[g * HD + col] / fmaxf(cnt, 1.f);
}

extern "C" void kernel_launch(void* const* d_in, const int* in_sizes, int n_in,
                              void* d_out, int out_size, void* d_ws, size_t ws_size,
                              hipStream_t stream) {
    const float* x = (const float*)d_in[0];
    const int* ei = (const int*)d_in[1];
    const int* batch = (const int*)d_in[2];
    const float* W1_0 = (const float*)d_in[3];
    const float* b1_0 = (const float*)d_in[4];
    const float* W2_0 = (const float*)d_in[5];
    const float* b2_0 = (const float*)d_in[6];
    const float* g_0 = (const float*)d_in[7];
    const float* be_0 = (const float*)d_in[8];
    const float* W1_1 = (const float*)d_in[9];
    const float* b1_1 = (const float*)d_in[10];
    const float* W2_1 = (const float*)d_in[11];
    const float* b2_1 = (const float*)d_in[12];
    const float* g_1 = (const float*)d_in[13];
    const float* be_1 = (const float*)d_in[14];

    float* out = (float*)d_out;  // raw L0 h2 -> raw L1 h2 -> final normalized

    // workspace layout (~20 MB)
    float* stats0 = (float*)d_ws;                      // 128 f32
    float* stats1 = stats0 + 128;                      // 128 f32
    float* psums = stats1 + 128;                       // 1024 f32
    int* cnt = (int*)(psums + 1024);                   // NN int
    unsigned short* csr = (unsigned short*)(cnt + NN); // NN*ROWCAP u16 (6.4 MB)
    __hip_bfloat16* xb = (__hip_bfloat16*)(csr + (size_t)NN * ROWCAP);   // bf16 x
    __hip_bfloat16* xb2 = xb + (size_t)NN * HD;        // bf16 raw L0 (separate!)

    dim3 b256(256);
    dim3 b512(512);
    int layer_grid = (NN + 127) / 128;            // 391
    int norm_grid = (NN * HD / 4 + 255) / 256;    // 3125
    int sct_grid = ((NE + 1023) / 1024) * NPART;  // 782 chunks x 8 = 6256

    // ---- padded-CSR build (2 dispatches) ----
    prep_kernel<<<norm_grid, b256, 0, stream>>>(x, xb, cnt, stats0, stats1, psums);
    scatter_kernel<<<sct_grid, b256, 0, stream>>>(ei, cnt, csr);

    // ---- layer 0 (agg fused into MLP; writes bf16 raw L0 into xb2) ----
    layer_kernel<0><<<layer_grid, b512, 0, stream>>>(
        x, xb, cnt, csr, nullptr, nullptr, nullptr,
        W1_0, b1_0, W2_0, b2_0, out, stats0, xb2);

    // ---- layer 1 (applies layer-0 BN+ReLU on the fly; gathers from xb2) ----
    layer_kernel<1><<<layer_grid, b512, 0, stream>>>(
        out, xb2, cnt, csr, stats0, g_0, be_0,
        W1_1, b1_1, W2_1, b2_1, out, stats1, (__hip_bfloat16*)nullptr);

    // ---- final norm + fused pool partials, then tiny finalize ----
    norm_kernel<<<norm_grid, b256, 0, stream>>>(out, stats1, g_1, be_1, batch, psums);
    pool_finalize_kernel<<<1, dim3(1024), 0, stream>>>(psums, batch, out + (size_t)NN * HD);
}

// Round 5
// 278.600 us; speedup vs baseline: 1.0233x; 1.0233x over previous
//
#include <hip/hip_runtime.h>
#include <hip/hip_bf16.h>

// GIN: 2 x (padded-CSR gather-sum fused with MLP(64->64->64) + BN-stats) + mean pool
// N=50000 nodes, E=800000 edges, H=64, G=16 graphs. fp32 in/out.
// R19 = R18 + occupancy fix: R18's 54KB LDS capped the fused kernel at
// 2 blocks/CU = 16 waves/CU and the random gather is latency-bound (occ 27%,
// 66us/layer). W/b GEMM accesses are wave-uniform -> scalar s_load direct
// from global (L2-resident, 16KB); sW/sb staging deleted. LDS 54.3->37.4KB
// -> 4 blocks/CU = 32 waves/CU, 2x outstanding gathers.
// 6 dispatches: prep, scatter, layer0, layer1, norm, finalize.

constexpr int NN = 50000;
constexpr int NE = 800000;
constexpr int HD = 64;
constexpr int NG = 16;
constexpr float BN_EPS = 1e-5f;
constexpr int ROWCAP = 64;   // max degree capacity; P(deg>64)~1e-20 at E/N=16
constexpr int NPART = 8;     // XCD partitions (scatter locality)
constexpr int PSZ = 6250;    // rows per partition

__device__ __forceinline__ int rdl(int v, int l) {
    return __builtin_amdgcn_readlane(v, l);
}

// ---------------------------------------------------------------------------
// Prep: fp32 -> bf16 table conversion; zero cnt[], stats0/1, psums.
// ---------------------------------------------------------------------------
__global__ __launch_bounds__(256)
void prep_kernel(const float* __restrict__ x, __hip_bfloat16* __restrict__ xb,
                 int* __restrict__ cnt, float* __restrict__ stats0,
                 float* __restrict__ stats1, float* __restrict__ psums) {
    int i4 = blockIdx.x * 256 + threadIdx.x;
    if (i4 < NN) cnt[i4] = 0;
    if (blockIdx.x == 0) {
        if (threadIdx.x < 128) stats0[threadIdx.x] = 0.f;
        else stats1[threadIdx.x - 128] = 0.f;
    } else if (blockIdx.x == 1) {
        *(float4*)(psums + threadIdx.x * 4) = make_float4(0.f, 0.f, 0.f, 0.f);
    }
    if (i4 >= NN * HD / 4) return;
    float4 v = *(const float4*)(x + (size_t)i4 * 4);
    union { ushort4 u; __hip_bfloat16 b[4]; } p;
    p.b[0] = __float2bfloat16(v.x);
    p.b[1] = __float2bfloat16(v.y);
    p.b[2] = __float2bfloat16(v.z);
    p.b[3] = __float2bfloat16(v.w);
    *(ushort4*)((unsigned short*)xb + (size_t)i4 * 4) = p.u;
}

// ---------------------------------------------------------------------------
// XCD-partitioned scatter into degree-padded ushort CSR (R16, unchanged).
// Block b: partition b&7 (round-robin blockIdx->XCD), edge chunk b>>3.
// ---------------------------------------------------------------------------
__global__ __launch_bounds__(256)
void scatter_kernel(const int* __restrict__ ei, int* __restrict__ cnt,
                    unsigned short* __restrict__ csr) {
    int p = blockIdx.x & 7;
    int chunk = blockIdx.x >> 3;
    int e4 = (chunk * 256 + threadIdx.x) * 4;
    if (e4 >= NE) return;
    int4 s = *(const int4*)(ei + e4);
    int4 d = *(const int4*)(ei + NE + e4);
    int lo = p * PSZ, hi = lo + PSZ;
    int slot;
    if (d.x >= lo && d.x < hi) {
        slot = atomicAdd(&cnt[d.x], 1);
        if (slot < ROWCAP) csr[(d.x << 6) + slot] = (unsigned short)s.x;
    }
    if (d.y >= lo && d.y < hi) {
        slot = atomicAdd(&cnt[d.y], 1);
        if (slot < ROWCAP) csr[(d.y << 6) + slot] = (unsigned short)s.y;
    }
    if (d.z >= lo && d.z < hi) {
        slot = atomicAdd(&cnt[d.z], 1);
        if (slot < ROWCAP) csr[(d.z << 6) + slot] = (unsigned short)s.z;
    }
    if (d.w >= lo && d.w < hi) {
        slot = atomicAdd(&cnt[d.w], 1);
        if (slot < ROWCAP) csr[(d.w << 6) + slot] = (unsigned short)s.w;
    }
}

// ---------------------------------------------------------------------------
// Fused layer kernel: aggregate 128 rows into LDS, then MLP + BN-stats.
// MODE 0: self/gather raw (layer 0).  MODE 1: apply prev BN+ReLU on the fly.
// 512 threads = 8 waves; wave w aggregates rows [w*16, w*16+16) and computes
// output cols [w*8, w*8+8). W/b read via wave-uniform scalar loads (no LDS
// staging): LDS 37.4KB -> 4 blocks/CU -> 32 waves/CU for the gather phase.
// xg (gather table) and xbr (bf16 output table) MUST be distinct buffers.
// ---------------------------------------------------------------------------
template <int MODE>
__global__ __launch_bounds__(512)
void layer_kernel(const float* __restrict__ xin, const __hip_bfloat16* __restrict__ xg,
                  const int* __restrict__ cnt, const unsigned short* __restrict__ csr,
                  const float* __restrict__ stats_prev, const float* __restrict__ gp,
                  const float* __restrict__ bep,
                  const float* __restrict__ W1, const float* __restrict__ b1,
                  const float* __restrict__ W2, const float* __restrict__ b2,
                  float* __restrict__ hout, float* __restrict__ stats,
                  __hip_bfloat16* __restrict__ xbr) {
    __shared__ float sh[128 * 65];
    __shared__ float red[2][8][64];
    int tid = threadIdx.x;
    int base = blockIdx.x * 128;
    int w = tid >> 6, lane = tid & 63;
    int wu = __builtin_amdgcn_readfirstlane(w);  // wave-uniform -> SGPR

    float sc = 1.f, off = 0.f;
    if (MODE == 1) {
        const float inv = 1.f / (float)NN;
        float mu = stats_prev[lane] * inv;
        float var = stats_prev[64 + lane] * inv - mu * mu;
        sc = gp[lane] * rsqrtf(var + BN_EPS);
        off = bep[lane] - mu * sc;
    }

    // ---- aggregation: wave w fills sh rows [w*16, w*16+16) ----
    for (int rl = wu * 16; rl < wu * 16 + 16; rl++) {
        int grow = base + rl;
        float acc = 0.f;
        if (grow < NN) {
            int m = min(cnt[grow], ROWCAP);
            int ids = (int)csr[((size_t)grow << 6) + lane];
            float sv = xin[(size_t)grow * HD + lane];
            acc = (MODE == 1) ? fmaxf(fmaf(sv, sc, off), 0.f) : sv;
            int j = 0;
            float a0 = 0.f, a1 = 0.f, a2 = 0.f, a3 = 0.f;
            float a4 = 0.f, a5 = 0.f, a6 = 0.f, a7 = 0.f;
            for (; j + 8 <= m; j += 8) {
                int n0 = rdl(ids, j);
                int n1 = rdl(ids, j + 1);
                int n2 = rdl(ids, j + 2);
                int n3 = rdl(ids, j + 3);
                int n4 = rdl(ids, j + 4);
                int n5 = rdl(ids, j + 5);
                int n6 = rdl(ids, j + 6);
                int n7 = rdl(ids, j + 7);
                float v0 = __bfloat162float(xg[((size_t)n0 << 6) + lane]);
                float v1 = __bfloat162float(xg[((size_t)n1 << 6) + lane]);
                float v2 = __bfloat162float(xg[((size_t)n2 << 6) + lane]);
                float v3 = __bfloat162float(xg[((size_t)n3 << 6) + lane]);
                float v4 = __bfloat162float(xg[((size_t)n4 << 6) + lane]);
                float v5 = __bfloat162float(xg[((size_t)n5 << 6) + lane]);
                float v6 = __bfloat162float(xg[((size_t)n6 << 6) + lane]);
                float v7 = __bfloat162float(xg[((size_t)n7 << 6) + lane]);
                if (MODE == 1) {
                    a0 += fmaxf(fmaf(v0, sc, off), 0.f);
                    a1 += fmaxf(fmaf(v1, sc, off), 0.f);
                    a2 += fmaxf(fmaf(v2, sc, off), 0.f);
                    a3 += fmaxf(fmaf(v3, sc, off), 0.f);
                    a4 += fmaxf(fmaf(v4, sc, off), 0.f);
                    a5 += fmaxf(fmaf(v5, sc, off), 0.f);
                    a6 += fmaxf(fmaf(v6, sc, off), 0.f);
                    a7 += fmaxf(fmaf(v7, sc, off), 0.f);
                } else {
                    a0 += v0; a1 += v1; a2 += v2; a3 += v3;
                    a4 += v4; a5 += v5; a6 += v6; a7 += v7;
                }
            }
            acc += ((a0 + a1) + (a2 + a3)) + ((a4 + a5) + (a6 + a7));
            for (; j < m; j++) {
                int nb = rdl(ids, j);
                float v = __bfloat162float(xg[((size_t)nb << 6) + lane]);
                acc += (MODE == 1) ? fmaxf(fmaf(v, sc, off), 0.f) : v;
            }
        }
        sh[rl * 65 + lane] = acc;
    }
    __syncthreads();

    // ---- GEMM1: wave w -> output cols [wu*8, wu*8+8); W via scalar loads ----
    float acc0[8], acc1[8];
#pragma unroll
    for (int j = 0; j < 8; j++) { acc0[j] = b1[wu * 8 + j]; acc1[j] = acc0[j]; }
    for (int k = 0; k < 64; k++) {
        float a0 = sh[lane * 65 + k];
        float a1 = sh[(64 + lane) * 65 + k];
        const float4* wr = (const float4*)(W1 + k * 64 + wu * 8);
#pragma unroll
        for (int q = 0; q < 2; q++) {
            float4 wv = wr[q];
            acc0[4 * q + 0] = fmaf(a0, wv.x, acc0[4 * q + 0]);
            acc0[4 * q + 1] = fmaf(a0, wv.y, acc0[4 * q + 1]);
            acc0[4 * q + 2] = fmaf(a0, wv.z, acc0[4 * q + 2]);
            acc0[4 * q + 3] = fmaf(a0, wv.w, acc0[4 * q + 3]);
            acc1[4 * q + 0] = fmaf(a1, wv.x, acc1[4 * q + 0]);
            acc1[4 * q + 1] = fmaf(a1, wv.y, acc1[4 * q + 1]);
            acc1[4 * q + 2] = fmaf(a1, wv.z, acc1[4 * q + 2]);
            acc1[4 * q + 3] = fmaf(a1, wv.w, acc1[4 * q + 3]);
        }
    }
    __syncthreads();

    // t = ReLU(acc) overwrites sh
#pragma unroll
    for (int j = 0; j < 8; j++) {
        sh[lane * 65 + wu * 8 + j] = fmaxf(acc0[j], 0.f);
        sh[(64 + lane) * 65 + wu * 8 + j] = fmaxf(acc1[j], 0.f);
    }
    __syncthreads();

    // ---- GEMM2 ----
#pragma unroll
    for (int j = 0; j < 8; j++) { acc0[j] = b2[wu * 8 + j]; acc1[j] = acc0[j]; }
    for (int k = 0; k < 64; k++) {
        float a0 = sh[lane * 65 + k];
        float a1 = sh[(64 + lane) * 65 + k];
        const float4* wr = (const float4*)(W2 + k * 64 + wu * 8);
#pragma unroll
        for (int q = 0; q < 2; q++) {
            float4 wv = wr[q];
            acc0[4 * q + 0] = fmaf(a0, wv.x, acc0[4 * q + 0]);
            acc0[4 * q + 1] = fmaf(a0, wv.y, acc0[4 * q + 1]);
            acc0[4 * q + 2] = fmaf(a0, wv.z, acc0[4 * q + 2]);
            acc0[4 * q + 3] = fmaf(a0, wv.w, acc0[4 * q + 3]);
            acc1[4 * q + 0] = fmaf(a1, wv.x, acc1[4 * q + 0]);
            acc1[4 * q + 1] = fmaf(a1, wv.y, acc1[4 * q + 1]);
            acc1[4 * q + 2] = fmaf(a1, wv.z, acc1[4 * q + 2]);
            acc1[4 * q + 3] = fmaf(a1, wv.w, acc1[4 * q + 3]);
        }
    }
    __syncthreads();
#pragma unroll
    for (int j = 0; j < 8; j++) {
        sh[lane * 65 + wu * 8 + j] = acc0[j];
        sh[(64 + lane) * 65 + wu * 8 + j] = acc1[j];
    }
    __syncthreads();

    // ---- coalesced stores: fp32 always; bf16 raw table if requested ----
#pragma unroll
    for (int i = 0; i < 4; i++) {
        int i4 = tid + 512 * i;
        int row = i4 >> 4, col = (i4 & 15) * 4;
        int grow = base + row;
        if (grow < NN) {
            const float* s = sh + row * 65 + col;
            float4 v = make_float4(s[0], s[1], s[2], s[3]);
            *(float4*)(hout + (size_t)grow * HD + col) = v;
            if (xbr) {
                union { ushort4 u; __hip_bfloat16 b[4]; } p;
                p.b[0] = __float2bfloat16(v.x);
                p.b[1] = __float2bfloat16(v.y);
                p.b[2] = __float2bfloat16(v.z);
                p.b[3] = __float2bfloat16(v.w);
                *(ushort4*)((unsigned short*)xbr + (size_t)grow * HD + col) = p.u;
            }
        }
    }

    // ---- fused BN-stats partials (wave w sums its 16 rows) ----
    {
        float s = 0.f, ss = 0.f;
#pragma unroll
        for (int r = 0; r < 16; r++) {
            int rl = wu * 16 + r;
            float v = (base + rl < NN) ? sh[rl * 65 + lane] : 0.f;
            s += v;
            ss += v * v;
        }
        red[0][wu][lane] = s;
        red[1][wu][lane] = ss;
        __syncthreads();
        if (tid < 64) {
            float S = 0.f;
#pragma unroll
            for (int q = 0; q < 8; q++) S += red[0][q][tid];
            atomicAdd(stats + tid, S);
        } else if (tid < 128) {
            int c = tid - 64;
            float SS = 0.f;
#pragma unroll
            for (int q = 0; q < 8; q++) SS += red[1][q][c];
            atomicAdd(stats + 64 + c, SS);
        }
    }
}

// ---------------------------------------------------------------------------
// Final BatchNorm + affine + ReLU, in-place on out, with fused mean-pool
// partials (LDS-reduce per-graph column sums, fire-and-forget atomics).
// ---------------------------------------------------------------------------
__global__ __launch_bounds__(256)
void norm_kernel(float* h, const float* __restrict__ stats,
                 const float* __restrict__ g, const float* __restrict__ be,
                 const int* __restrict__ batch, float* __restrict__ psums) {
    __shared__ float sg[2][64];
    if (threadIdx.x < 128) sg[threadIdx.x >> 6][threadIdx.x & 63] = 0.f;
    __syncthreads();
    size_t i4 = (size_t)blockIdx.x * 256 + threadIdx.x;
    int row = (int)(i4 >> 4);            // 16 threads (4 cols each) per row
    int base_row = blockIdx.x * 16;
    int g0 = batch[base_row];
    size_t off = i4 * 4;
    int col = (int)(off & 63);
    float4 v = *(const float4*)(h + off);
    float4 sm = *(const float4*)(stats + col);
    float4 sq = *(const float4*)(stats + 64 + col);
    float4 gg = *(const float4*)(g + col);
    float4 bb = *(const float4*)(be + col);
    const float inv = 1.f / (float)NN;
    float4 o;
    {
        float mu = sm.x * inv, var = sq.x * inv - mu * mu;
        float sc = gg.x * rsqrtf(var + BN_EPS);
        o.x = fmaxf((v.x - mu) * sc + bb.x, 0.f);
    }
    {
        float mu = sm.y * inv, var = sq.y * inv - mu * mu;
        float sc = gg.y * rsqrtf(var + BN_EPS);
        o.y = fmaxf((v.y - mu) * sc + bb.y, 0.f);
    }
    {
        float mu = sm.z * inv, var = sq.z * inv - mu * mu;
        float sc = gg.z * rsqrtf(var + BN_EPS);
        o.z = fmaxf((v.z - mu) * sc + bb.z, 0.f);
    }
    {
        float mu = sm.w * inv, var = sq.w * inv - mu * mu;
        float sc = gg.w * rsqrtf(var + BN_EPS);
        o.w = fmaxf((v.w - mu) * sc + bb.w, 0.f);
    }
    *(float4*)(h + off) = o;

    // pool partials
    int dg = batch[row] - g0;
    if (dg <= 1) {
        atomicAdd(&sg[dg][col + 0], o.x);
        atomicAdd(&sg[dg][col + 1], o.y);
        atomicAdd(&sg[dg][col + 2], o.z);
        atomicAdd(&sg[dg][col + 3], o.w);
    } else {  // >2 graphs in one 16-row window (never at ~3125 rows/graph)
        int gid = g0 + dg;
        atomicAdd(&psums[gid * HD + col + 0], o.x);
        atomicAdd(&psums[gid * HD + col + 1], o.y);
        atomicAdd(&psums[gid * HD + col + 2], o.z);
        atomicAdd(&psums[gid * HD + col + 3], o.w);
    }
    __syncthreads();
    if (threadIdx.x < 128) {
        int d = threadIdx.x >> 6;
        int c = threadIdx.x & 63;
        float s = sg[d][c];
        if (g0 + d < NG && s != 0.f) atomicAdd(&psums[(g0 + d) * HD + c], s);
    }
}

// ---------------------------------------------------------------------------
// Pool finalize: divide psums by graph sizes (batch sorted -> binary search).
// ---------------------------------------------------------------------------
__device__ __forceinline__ int lower_bound_batch(const int* __restrict__ b, int val) {
    int lo = 0, hi = NN;
    while (lo < hi) {
        int mid = (lo + hi) >> 1;
        if (b[mid] < val) lo = mid + 1;
        else hi = mid;
    }
    return lo;
}

__global__ __launch_bounds__(1024)
void pool_finalize_kernel(const float* __restrict__ sums, const int* __restrict__ batch,
                          float* __restrict__ out) {
    int g = threadIdx.x >> 6;
    int col = threadIdx.x & 63;
    int s = lower_bound_batch(batch, g);
    int e = lower_bound_batch(batch, g + 1);
    float cnt = (float)(e - s);
    out[g * HD + col] = sums[g * HD + col] / fmaxf(cnt, 1.f);
}

extern "C" void kernel_launch(void* const* d_in, const int* in_sizes, int n_in,
                              void* d_out, int out_size, void* d_ws, size_t ws_size,
                              hipStream_t stream) {
    const float* x = (const float*)d_in[0];
    const int* ei = (const int*)d_in[1];
    const int* batch = (const int*)d_in[2];
    const float* W1_0 = (const float*)d_in[3];
    const float* b1_0 = (const float*)d_in[4];
    const float* W2_0 = (const float*)d_in[5];
    const float* b2_0 = (const float*)d_in[6];
    const float* g_0 = (const float*)d_in[7];
    const float* be_0 = (const float*)d_in[8];
    const float* W1_1 = (const float*)d_in[9];
    const float* b1_1 = (const float*)d_in[10];
    const float* W2_1 = (const float*)d_in[11];
    const float* b2_1 = (const float*)d_in[12];
    const float* g_1 = (const float*)d_in[13];
    const float* be_1 = (const float*)d_in[14];

    float* out = (float*)d_out;  // raw L0 h2 -> raw L1 h2 -> final normalized

    // workspace layout (~20 MB)
    float* stats0 = (float*)d_ws;                      // 128 f32
    float* stats1 = stats0 + 128;                      // 128 f32
    float* psums = stats1 + 128;                       // 1024 f32
    int* cnt = (int*)(psums + 1024);                   // NN int
    unsigned short* csr = (unsigned short*)(cnt + NN); // NN*ROWCAP u16 (6.4 MB)
    __hip_bfloat16* xb = (__hip_bfloat16*)(csr + (size_t)NN * ROWCAP);   // bf16 x
    __hip_bfloat16* xb2 = xb + (size_t)NN * HD;        // bf16 raw L0 (separate!)

    dim3 b256(256);
    dim3 b512(512);
    int layer_grid = (NN + 127) / 128;            // 391
    int norm_grid = (NN * HD / 4 + 255) / 256;    // 3125
    int sct_grid = ((NE + 1023) / 1024) * NPART;  // 782 chunks x 8 = 6256

    // ---- padded-CSR build (2 dispatches) ----
    prep_kernel<<<norm_grid, b256, 0, stream>>>(x, xb, cnt, stats0, stats1, psums);
    scatter_kernel<<<sct_grid, b256, 0, stream>>>(ei, cnt, csr);

    // ---- layer 0 (agg fused into MLP; writes bf16 raw L0 into xb2) ----
    layer_kernel<0><<<layer_grid, b512, 0, stream>>>(
        x, xb, cnt, csr, nullptr, nullptr, nullptr,
        W1_0, b1_0, W2_0, b2_0, out, stats0, xb2);

    // ---- layer 1 (applies layer-0 BN+ReLU on the fly; gathers from xb2) ----
    layer_kernel<1><<<layer_grid, b512, 0, stream>>>(
        out, xb2, cnt, csr, stats0, g_0, be_0,
        W1_1, b1_1, W2_1, b2_1, out, stats1, (__hip_bfloat16*)nullptr);

    // ---- final norm + fused pool partials, then tiny finalize ----
    norm_kernel<<<norm_grid, b256, 0, stream>>>(out, stats1, g_1, be_1, batch, psums);
    pool_finalize_kernel<<<1, dim3(1024), 0, stream>>>(psums, batch, out + (size_t)NN * HD);
}